// Round 14
// baseline (706.617 us; speedup 1.0000x reference)
//
#include <hip/hip_runtime.h>
#include <hip/hip_cooperative_groups.h>

namespace cg = cooperative_groups;

#define N_NODES  10000
#define N_EDGES  320000
#define N_GRAPHS 64
#define STRIDE   192   // padded adjacency row length (mean deg 32, P(deg>192) ~ 0)

// prep role partition
#define RB 625    // repack+scatter units (2 edges/thread: 320000/512)
#define RQ 157    // q1 units (ceil(10000/64))
#define RW 256    // w2-split units (512*128/256)

typedef __attribute__((ext_vector_type(8))) __bf16 bf16x8;
typedef __attribute__((ext_vector_type(4))) float f32x4;
typedef __attribute__((ext_vector_type(4))) unsigned int u32x4;

__device__ __forceinline__ float sigm(float z) { return 1.0f / (1.0f + __expf(-z)); }

__device__ __forceinline__ unsigned short f2bf(float f) {
    unsigned int u = __float_as_uint(f);
    return (unsigned short)((u + 0x7fffu + ((u >> 16) & 1u)) >> 16);
}
__device__ __forceinline__ float bf2f(unsigned short h) { return __uint_as_float(((unsigned int)h) << 16); }
__device__ __forceinline__ float bflo(unsigned int u) { return __uint_as_float(u << 16); }
__device__ __forceinline__ float bfhi(unsigned int u) { return __uint_as_float(u & 0xffff0000u); }

// ================= MEGA KERNEL: whole pipeline, one launch, 6 phases =================
// P0 zero -> P1 prep -> P2 econv1 -> P3 gemm2(32x32 tiles, 32KB LDS) -> P4 econv2 -> P5 final
__global__ __launch_bounds__(256) void mega_k(
        const unsigned int* __restrict__ ei_raw, const unsigned int* __restrict__ b_raw,
        const float* __restrict__ x, const float* __restrict__ W1, const float* __restrict__ b1,
        const float* __restrict__ W2, const float* __restrict__ b2,
        const float* __restrict__ W3, const float* __restrict__ b3,
        const float* __restrict__ W4, const float* __restrict__ b4,
        int* __restrict__ bat, int* __restrict__ cnt, unsigned short* __restrict__ csr_pad,
        unsigned short* __restrict__ Q1,
        unsigned short* __restrict__ h1h, unsigned short* __restrict__ h1l,
        unsigned short* __restrict__ Bh, unsigned short* __restrict__ Bl,
        float* __restrict__ P2, unsigned short* __restrict__ Q2,
        float* __restrict__ g, float* __restrict__ out) {
    cg::grid_group grid = cg::this_grid();
    __shared__ __align__(16) char smem[32768];
    int t = threadIdx.x;
    int bid = blockIdx.x, gsz = gridDim.x;
    int gid = bid * 256 + t, gstride = gsz * 256;

    // ---------------- P0: zero cnt and g ----------------
    for (int i = gid; i < N_NODES; i += gstride) cnt[i] = 0;
    for (int i = gid; i < N_GRAPHS * 256; i += gstride) g[i] = 0.f;
    grid.sync();

    // ---------------- P1: prep roles (block-stride) ----------------
    for (int u = bid; u < RB + RQ + RW; u += gsz) {
        if (u < RB) {
            int* snz = (int*)smem;
            if (t < 2) snz[t] = 0;
            __syncthreads();
            {
                unsigned int wv = ei_raw[u * 1024 + 2 * t + 1];   // max 624*1024+511 < 640000
                unsigned long long m = __ballot(wv != 0);
                if ((t & 63) == 0 && m) atomicAdd(&snz[0], __popcll(m));
            }
            if (u * 256 < N_NODES) {
                int w0 = min(u * 512, N_NODES - 512);
                unsigned int bv = b_raw[w0 + 2 * t + 1];
                unsigned long long m = __ballot(bv != 0);
                if ((t & 63) == 0 && m) atomicAdd(&snz[1], __popcll(m));
            }
            __syncthreads();
            int i32e = snz[0] > 16, i32b = snz[1] > 16;
            const int* ei = (const int*)ei_raw;
            int e0 = u * 512 + 2 * t;   // e0, e0+1 < 320000 (625*512 = 320000)
            int s0, s1, d0, d1;
            if (i32e) {
                uint2 sv = *(const uint2*)&ei[e0];
                uint2 dv = *(const uint2*)&ei[N_EDGES + e0];
                s0 = sv.x; s1 = sv.y; d0 = dv.x; d1 = dv.y;
            } else {
                uint4 sv = *(const uint4*)&ei[2 * e0];
                uint4 dv = *(const uint4*)&ei[2 * (N_EDGES + e0)];
                s0 = sv.x; s1 = sv.z; d0 = dv.x; d1 = dv.z;
            }
            int slot = atomicAdd(&cnt[d0], 1);
            if (slot < STRIDE) csr_pad[d0 * STRIDE + slot] = (unsigned short)s0;
            slot = atomicAdd(&cnt[d1], 1);
            if (slot < STRIDE) csr_pad[d1 * STRIDE + slot] = (unsigned short)s1;
            int i = u * 256 + t;
            if (i < N_NODES) {
                const int* bb = (const int*)b_raw;
                bat[i] = i32b ? bb[i] : bb[2 * i];
            }
        } else if (u < RB + RQ) {
            float* xs = (float*)smem;
            int c = t & 127, half = t >> 7;
            float k0 = W1[384 + c];
            float k1 = W1[512 + c];
            float k2 = W1[640 + c];
            int n0 = (u - RB) * 64;
            int nmax = min(64, N_NODES - n0);
            if (t < 192) xs[t] = (t < nmax * 3) ? x[n0 * 3 + t] : 0.f;
            __syncthreads();
            for (int tt = 0; tt < 32; tt++) {
                int ln = 2 * tt + half;
                if (ln < nmax) {
                    float v = xs[ln * 3 + 0] * k0 + xs[ln * 3 + 1] * k1 + xs[ln * 3 + 2] * k2;
                    Q1[(n0 + ln) * 128 + c] = f2bf(v);
                }
            }
        } else {
            int idx = (u - RB - RQ) * 256 + t;
            int nn = idx >> 7, k = idx & 127;
            float wc;
            if (nn < 256) wc = W2[k * 256 + nn] - W2[(128 + k) * 256 + nn];
            else          wc = W2[(128 + k) * 256 + (nn - 256)];
            unsigned short h = f2bf(wc);
            Bh[idx] = h;
            Bl[idx] = f2bf(wc - bf2f(h));
        }
        __syncthreads();   // block-uniform: protect smem reuse across role units
    }
    grid.sync();

    // ---------------- P2: econv1 (4 waves/block = 4 nodes; 16-deep gather) ----------------
    for (int u = bid; u < N_NODES / 4; u += gsz) {
        int lane = t & 63;
        int i = u * 4 + (t >> 6);
        int e = min(cnt[i], STRIDE);
        int c0 = 2 * lane, c1 = c0 + 1;
        float x0 = x[i * 3 + 0], x1 = x[i * 3 + 1], x2 = x[i * 3 + 2];
        float bb0 = b1[c0], bb1 = b1[c1];
        float wa0 = W1[c0] - W1[384 + c0];
        float wb0 = W1[128 + c0] - W1[512 + c0];
        float wc0 = W1[256 + c0] - W1[640 + c0];
        float wa1 = W1[c1] - W1[384 + c1];
        float wb1 = W1[128 + c1] - W1[512 + c1];
        float wc1 = W1[256 + c1] - W1[640 + c1];
        float o0 = 0.f, o1 = 0.f;
        if (e > 0) {
            const unsigned short* row = csr_pad + (size_t)i * STRIDE;
            float z0 = -3.4e38f, z1 = -3.4e38f;
            int last = e - 1;
            for (int k = 0; k < e; k += 16) {
                uint4 ra = *(const uint4*)&row[k];
                uint4 rb = *(const uint4*)&row[k + 8];
                unsigned int rw[8] = {ra.x, ra.y, ra.z, ra.w, rb.x, rb.y, rb.z, rb.w};
                int j0 = rw[0] & 0xffff;
                unsigned int uu[16];
#pragma unroll
                for (int tt = 0; tt < 16; tt++) {
                    int raw = (rw[tt >> 1] >> ((tt & 1) * 16)) & 0xffff;
                    int j = (k + tt <= last) ? raw : j0;  // dup-pad: max is idempotent
                    uu[tt] = ((const unsigned int*)Q1)[j * 64 + lane];
                }
#pragma unroll
                for (int tt = 0; tt < 16; tt++) {
                    z0 = fmaxf(z0, bflo(uu[tt]));
                    z1 = fmaxf(z1, bfhi(uu[tt]));
                }
            }
            float p0 = bb0 + x0 * wa0 + x1 * wb0 + x2 * wc0;
            float p1 = bb1 + x0 * wa1 + x1 * wb1 + x2 * wc1;
            o0 = sigm(p0 + z0);
            o1 = sigm(p1 + z1);
        }
        unsigned short hh0 = f2bf(o0), hh1 = f2bf(o1);
        unsigned short hl0 = f2bf(o0 - bf2f(hh0)), hl1 = f2bf(o1 - bf2f(hh1));
        *(ushort2*)&h1h[i * 128 + 2 * lane] = make_ushort2(hh0, hh1);
        *(ushort2*)&h1l[i * 128 + 2 * lane] = make_ushort2(hl0, hl1);
    }
    grid.sync();

    // ---------------- P3: gemm2 split-bf16 MFMA, 32x32 tiles (32KB LDS) ----------------
    {
        char* Ahb = smem;
        char* Alb = smem + 8192;
        char* Bhb = smem + 16384;
        char* Blb = smem + 24576;
        int w = t >> 6, lane = t & 63;
        int lr = lane & 15, lg = lane >> 4;
        for (int u = bid; u < 313 * 16; u += gsz) {
            int m0 = (u >> 4) * 32, n0 = (u & 15) * 32;
#pragma unroll
            for (int it = 0; it < 2; it++) {
                int c = t + it * 256;          // 0..511
                int row = c >> 4, kb = c & 15; // row 0..31
                int dsa = (row * 256 + kb * 16) ^ ((row & 7) << 4);
                u32x4 va = {0u, 0u, 0u, 0u}, vl = {0u, 0u, 0u, 0u};
                if (m0 + row < N_NODES) {
                    va = *(const u32x4*)&h1h[(m0 + row) * 128 + kb * 8];
                    vl = *(const u32x4*)&h1l[(m0 + row) * 128 + kb * 8];
                }
                *(u32x4*)(Ahb + dsa) = va;
                *(u32x4*)(Alb + dsa) = vl;
                *(u32x4*)(Bhb + dsa) = *(const u32x4*)&Bh[(n0 + row) * 128 + kb * 8];
                *(u32x4*)(Blb + dsa) = *(const u32x4*)&Bl[(n0 + row) * 128 + kb * 8];
            }
            __syncthreads();
            int am = 16 * (w & 1) + lr;
            int abase = am * 256 + lg * 16;
            int asw = (am & 7) << 4;
            bf16x8 ah[4], al[4];
#pragma unroll
            for (int kk = 0; kk < 4; kk++) {
                int off = (abase + kk * 64) ^ asw;
                ah[kk] = *(const bf16x8*)(Ahb + off);
                al[kk] = *(const bf16x8*)(Alb + off);
            }
            int nt = w >> 1;
            int bsw = (lr & 7) << 4;
            int nbase = (nt * 16 + lr) * 256 + lg * 16;
            f32x4 acc = {0.f, 0.f, 0.f, 0.f};
#pragma unroll
            for (int kk = 0; kk < 4; kk++) {
                int off = (nbase + kk * 64) ^ bsw;
                bf16x8 bh = *(const bf16x8*)(Bhb + off);
                bf16x8 bl = *(const bf16x8*)(Blb + off);
                acc = __builtin_amdgcn_mfma_f32_16x16x32_bf16(ah[kk], bh, acc, 0, 0, 0);
                acc = __builtin_amdgcn_mfma_f32_16x16x32_bf16(al[kk], bh, acc, 0, 0, 0);
                acc = __builtin_amdgcn_mfma_f32_16x16x32_bf16(ah[kk], bl, acc, 0, 0, 0);
            }
            int colg = n0 + nt * 16 + lr;
            int mbase = m0 + 16 * (w & 1) + 4 * lg;
            if (colg < 256) {
                float bias = b2[colg];
#pragma unroll
                for (int r = 0; r < 4; r++) {
                    int m = mbase + r;
                    if (m < N_NODES) P2[(size_t)m * 256 + colg] = acc[r] + bias;
                }
            } else {
                int qc = colg - 256;
#pragma unroll
                for (int r = 0; r < 4; r++) {
                    int m = mbase + r;
                    if (m < N_NODES) Q2[(size_t)m * 256 + qc] = f2bf(acc[r]);
                }
            }
            __syncthreads();
        }
    }
    grid.sync();

    // ---------------- P4: econv2 + graph max-pool with block pre-reduction ----------------
    for (int u = bid; u < N_NODES / 16; u += gsz) {
        int lane = t & 63;
        int w = t >> 6;
        int half = w & 1, slot = w >> 1;
        int cc = half * 64 + lane;
        int base = u * 16;
        float pm0 = 0.f, pm1 = 0.f;
        int curg = -1;
        for (int nn = slot; nn < 16; nn += 2) {
            int i = base + nn;
            int bi = bat[i];
            if (bi != curg) {
                if (curg >= 0 && pm0 > 0.f) {
                    int gb = curg * 256 + 2 * cc;
                    atomicMax((unsigned int*)&g[gb + 0], __float_as_uint(pm0));
                    atomicMax((unsigned int*)&g[gb + 1], __float_as_uint(pm1));
                }
                curg = bi;
                pm0 = 0.f;
                pm1 = 0.f;
            }
            int e = min(cnt[i], STRIDE);
            if (e == 0) continue;
            const unsigned short* row = csr_pad + (size_t)i * STRIDE;
            unsigned long long pv = *(const unsigned long long*)&P2[(size_t)i * 256 + 2 * cc];
            float z0 = -3.4e38f, z1 = -3.4e38f;
            int last = e - 1;
            for (int k = 0; k < e; k += 16) {
                uint4 ra = *(const uint4*)&row[k];
                uint4 rb = *(const uint4*)&row[k + 8];
                unsigned int rw[8] = {ra.x, ra.y, ra.z, ra.w, rb.x, rb.y, rb.z, rb.w};
                int j0 = rw[0] & 0xffff;
                unsigned int uu[16];
#pragma unroll
                for (int tt = 0; tt < 16; tt++) {
                    int raw = (rw[tt >> 1] >> ((tt & 1) * 16)) & 0xffff;
                    int j = (k + tt <= last) ? raw : j0;
                    uu[tt] = ((const unsigned int*)Q2)[j * 128 + cc];
                }
#pragma unroll
                for (int tt = 0; tt < 16; tt++) {
                    z0 = fmaxf(z0, bflo(uu[tt]));
                    z1 = fmaxf(z1, bfhi(uu[tt]));
                }
            }
            float px = __uint_as_float((unsigned int)pv);
            float py = __uint_as_float((unsigned int)(pv >> 32));
            pm0 = fmaxf(pm0, sigm(px + z0));
            pm1 = fmaxf(pm1, sigm(py + z1));
        }
        if (curg >= 0 && pm0 > 0.f) {
            int gb = curg * 256 + 2 * cc;
            atomicMax((unsigned int*)&g[gb + 0], __float_as_uint(pm0));
            atomicMax((unsigned int*)&g[gb + 1], __float_as_uint(pm1));
        }
    }
    grid.sync();

    // ---------------- P5: head ----------------
    {
        float* gs = (float*)smem;
        float* ss = (float*)(smem + 1024);
        for (int u = bid; u < N_GRAPHS; u += gsz) {
            gs[t] = g[u * 256 + t];
            __syncthreads();
            if (t < 128) {
                float acc = b3[t];
#pragma unroll 8
                for (int k = 0; k < 256; k++) acc += gs[k] * W3[k * 128 + t];
                ss[t] = sigm(acc);
            }
            __syncthreads();
            if (t < 10) {
                float o = b4[t];
#pragma unroll 8
                for (int k = 0; k < 128; k++) o += ss[k] * W4[k * 10 + t];
                out[u * 10 + t] = o;
            }
            __syncthreads();
        }
    }
}

// ================= FALLBACK PATH: r9 kernels (used only if cooperative launch fails) ====
__global__ __launch_bounds__(256) void prep_k(
        const unsigned int* __restrict__ ei_raw, const unsigned int* __restrict__ b_raw,
        const float* __restrict__ x, const float* __restrict__ W1,
        const float* __restrict__ W2,
        int* __restrict__ bat, int* __restrict__ cnt, unsigned short* __restrict__ csr_pad,
        unsigned short* __restrict__ Q1,
        unsigned short* __restrict__ Bh, unsigned short* __restrict__ Bl,
        float* __restrict__ g) {
    int bx = blockIdx.x, t = threadIdx.x;
    if (bx < RB) {
        __shared__ int snz[2];
        if (t < 2) snz[t] = 0;
        __syncthreads();
        {
            unsigned int wv = ei_raw[bx * 1024 + 2 * t + 1];
            unsigned long long m = __ballot(wv != 0);
            if ((t & 63) == 0 && m) atomicAdd(&snz[0], __popcll(m));
        }
        if (bx * 256 < N_NODES) {
            int w0 = min(bx * 512, N_NODES - 512);
            unsigned int bv = b_raw[w0 + 2 * t + 1];
            unsigned long long m = __ballot(bv != 0);
            if ((t & 63) == 0 && m) atomicAdd(&snz[1], __popcll(m));
        }
        __syncthreads();
        int i32e = snz[0] > 16;
        const int* ei = (const int*)ei_raw;
        int e0 = bx * 512 + 2 * t;
        int s0, s1, d0, d1;
        if (i32e) {
            uint2 sv = *(const uint2*)&ei[e0];
            uint2 dv = *(const uint2*)&ei[N_EDGES + e0];
            s0 = sv.x; s1 = sv.y; d0 = dv.x; d1 = dv.y;
        } else {
            uint4 sv = *(const uint4*)&ei[2 * e0];
            uint4 dv = *(const uint4*)&ei[2 * (N_EDGES + e0)];
            s0 = sv.x; s1 = sv.z; d0 = dv.x; d1 = dv.z;
        }
        int slot = atomicAdd(&cnt[d0], 1);
        if (slot < STRIDE) csr_pad[d0 * STRIDE + slot] = (unsigned short)s0;
        slot = atomicAdd(&cnt[d1], 1);
        if (slot < STRIDE) csr_pad[d1 * STRIDE + slot] = (unsigned short)s1;
        int i = bx * 256 + t;
        if (i < N_NODES) {
            int i32b = snz[1] > 16;
            const int* bb = (const int*)b_raw;
            bat[i] = i32b ? bb[i] : bb[2 * i];
        }
    } else if (bx < RB + RQ) {
        __shared__ float xs[192];
        int c = t & 127, half = t >> 7;
        float k0 = W1[384 + c];
        float k1 = W1[512 + c];
        float k2 = W1[640 + c];
        int n0 = (bx - RB) * 64;
        int nmax = min(64, N_NODES - n0);
        if (t < 192) xs[t] = (t < nmax * 3) ? x[n0 * 3 + t] : 0.f;
        __syncthreads();
        for (int tt = 0; tt < 32; tt++) {
            int ln = 2 * tt + half;
            if (ln < nmax) {
                float v = xs[ln * 3 + 0] * k0 + xs[ln * 3 + 1] * k1 + xs[ln * 3 + 2] * k2;
                Q1[(n0 + ln) * 128 + c] = f2bf(v);
            }
        }
    } else if (bx < RB + RQ + RW) {
        int idx = (bx - RB - RQ) * 256 + t;
        int nn = idx >> 7, k = idx & 127;
        float wc;
        if (nn < 256) wc = W2[k * 256 + nn] - W2[(128 + k) * 256 + nn];
        else          wc = W2[(128 + k) * 256 + (nn - 256)];
        unsigned short h = f2bf(wc);
        Bh[idx] = h;
        Bl[idx] = f2bf(wc - bf2f(h));
    } else {
        float4 z = make_float4(0.f, 0.f, 0.f, 0.f);
#pragma unroll
        for (int it = 0; it < 16; it++) *(float4*)&g[(t + it * 256) * 4] = z;
    }
}

__global__ __launch_bounds__(256) void econv1_k(
        const float* __restrict__ x, const float* __restrict__ W1, const float* __restrict__ b1,
        const unsigned int* __restrict__ Q1u,
        const int* __restrict__ cnt, const unsigned short* __restrict__ csr_pad,
        unsigned short* __restrict__ h1h, unsigned short* __restrict__ h1l) {
    int lane = threadIdx.x & 63;
    int i = blockIdx.x * 4 + (threadIdx.x >> 6);
    int e = min(cnt[i], STRIDE);
    int c0 = 2 * lane, c1 = c0 + 1;
    float x0 = x[i * 3 + 0], x1 = x[i * 3 + 1], x2 = x[i * 3 + 2];
    float bb0 = b1[c0], bb1 = b1[c1];
    float wa0 = W1[c0] - W1[384 + c0];
    float wb0 = W1[128 + c0] - W1[512 + c0];
    float wc0 = W1[256 + c0] - W1[640 + c0];
    float wa1 = W1[c1] - W1[384 + c1];
    float wb1 = W1[128 + c1] - W1[512 + c1];
    float wc1 = W1[256 + c1] - W1[640 + c1];
    float o0 = 0.f, o1 = 0.f;
    if (e > 0) {
        const unsigned short* row = csr_pad + (size_t)i * STRIDE;
        float z0 = -3.4e38f, z1 = -3.4e38f;
        int last = e - 1;
        for (int k = 0; k < e; k += 16) {
            uint4 ra = *(const uint4*)&row[k];
            uint4 rb = *(const uint4*)&row[k + 8];
            unsigned int rw[8] = {ra.x, ra.y, ra.z, ra.w, rb.x, rb.y, rb.z, rb.w};
            int j0 = rw[0] & 0xffff;
            unsigned int u[16];
#pragma unroll
            for (int tt = 0; tt < 16; tt++) {
                int raw = (rw[tt >> 1] >> ((tt & 1) * 16)) & 0xffff;
                int j = (k + tt <= last) ? raw : j0;
                u[tt] = Q1u[j * 64 + lane];
            }
#pragma unroll
            for (int tt = 0; tt < 16; tt++) {
                z0 = fmaxf(z0, bflo(u[tt]));
                z1 = fmaxf(z1, bfhi(u[tt]));
            }
        }
        float p0 = bb0 + x0 * wa0 + x1 * wb0 + x2 * wc0;
        float p1 = bb1 + x0 * wa1 + x1 * wb1 + x2 * wc1;
        o0 = sigm(p0 + z0);
        o1 = sigm(p1 + z1);
    }
    unsigned short hh0 = f2bf(o0), hh1 = f2bf(o1);
    unsigned short hl0 = f2bf(o0 - bf2f(hh0)), hl1 = f2bf(o1 - bf2f(hh1));
    *(ushort2*)&h1h[i * 128 + 2 * lane] = make_ushort2(hh0, hh1);
    *(ushort2*)&h1l[i * 128 + 2 * lane] = make_ushort2(hl0, hl1);
}

__global__ __launch_bounds__(256) void gemm2_k(
        const unsigned short* __restrict__ Ahg, const unsigned short* __restrict__ Alg,
        const unsigned short* __restrict__ Bhg, const unsigned short* __restrict__ Blg,
        const float* __restrict__ b2, float* __restrict__ P2,
        unsigned short* __restrict__ Q2, int n) {
    __shared__ __align__(16) char smem[65536];
    char* Ahb = smem;
    char* Alb = smem + 16384;
    char* Bhb = smem + 32768;
    char* Blb = smem + 49152;
    int t = threadIdx.x;
    int m0 = blockIdx.x * 64;
    int n0 = blockIdx.y * 64;
#pragma unroll
    for (int it = 0; it < 4; it++) {
        int c = t + it * 256;
        int row = c >> 4, kb = c & 15;
        int dsa = (row * 256 + kb * 16) ^ ((row & 7) << 4);
        u32x4 va = {0u, 0u, 0u, 0u}, vl = {0u, 0u, 0u, 0u};
        if (m0 + row < n) {
            va = *(const u32x4*)&Ahg[(m0 + row) * 128 + kb * 8];
            vl = *(const u32x4*)&Alg[(m0 + row) * 128 + kb * 8];
        }
        *(u32x4*)(Ahb + dsa) = va;
        *(u32x4*)(Alb + dsa) = vl;
        *(u32x4*)(Bhb + dsa) = *(const u32x4*)&Bhg[(n0 + row) * 128 + kb * 8];
        *(u32x4*)(Blb + dsa) = *(const u32x4*)&Blg[(n0 + row) * 128 + kb * 8];
    }
    __syncthreads();

    int w = t >> 6, lane = t & 63;
    int lr = lane & 15, lg = lane >> 4;
    int am = 16 * w + lr;
    int abase = am * 256 + lg * 16;
    int asw = (am & 7) << 4;
    bf16x8 ah[4], al[4];
#pragma unroll
    for (int kk = 0; kk < 4; kk++) {
        int off = (abase + kk * 64) ^ asw;
        ah[kk] = *(const bf16x8*)(Ahb + off);
        al[kk] = *(const bf16x8*)(Alb + off);
    }
    int bsw = (lr & 7) << 4;
#pragma unroll
    for (int nt = 0; nt < 4; nt++) {
        int nb = (nt * 16 + lr) * 256 + lg * 16;
        f32x4 acc = {0.f, 0.f, 0.f, 0.f};
#pragma unroll
        for (int kk = 0; kk < 4; kk++) {
            int off = (nb + kk * 64) ^ bsw;
            bf16x8 bh = *(const bf16x8*)(Bhb + off);
            bf16x8 bl = *(const bf16x8*)(Blb + off);
            acc = __builtin_amdgcn_mfma_f32_16x16x32_bf16(ah[kk], bh, acc, 0, 0, 0);
            acc = __builtin_amdgcn_mfma_f32_16x16x32_bf16(al[kk], bh, acc, 0, 0, 0);
            acc = __builtin_amdgcn_mfma_f32_16x16x32_bf16(ah[kk], bl, acc, 0, 0, 0);
        }
        int colg = n0 + nt * 16 + lr;
        int mbase = m0 + 16 * w + 4 * lg;
        if (colg < 256) {
            float bias = b2[colg];
#pragma unroll
            for (int r = 0; r < 4; r++) {
                int m = mbase + r;
                if (m < n) P2[(size_t)m * 256 + colg] = acc[r] + bias;
            }
        } else {
            int qc = colg - 256;
#pragma unroll
            for (int r = 0; r < 4; r++) {
                int m = mbase + r;
                if (m < n) Q2[(size_t)m * 256 + qc] = f2bf(acc[r]);
            }
        }
    }
}

__global__ __launch_bounds__(256) void econv2_k(
        const float* __restrict__ P2, const unsigned int* __restrict__ Q2u,
        const int* __restrict__ cnt, const unsigned short* __restrict__ csr_pad,
        const int* __restrict__ bat, float* __restrict__ g) {
    int lane = threadIdx.x & 63;
    int w = threadIdx.x >> 6;
    int half = w & 1, slot = w >> 1;
    int cc = half * 64 + lane;
    int base = blockIdx.x * 16;
    float m0 = 0.f, m1 = 0.f;
    int curg = -1;
    for (int nn = slot; nn < 16; nn += 2) {
        int i = base + nn;
        int bi = bat[i];
        if (bi != curg) {
            if (curg >= 0 && m0 > 0.f) {
                int gb = curg * 256 + 2 * cc;
                atomicMax((unsigned int*)&g[gb + 0], __float_as_uint(m0));
                atomicMax((unsigned int*)&g[gb + 1], __float_as_uint(m1));
            }
            curg = bi;
            m0 = 0.f;
            m1 = 0.f;
        }
        int e = min(cnt[i], STRIDE);
        if (e == 0) continue;
        const unsigned short* row = csr_pad + (size_t)i * STRIDE;
        unsigned long long pv = *(const unsigned long long*)&P2[(size_t)i * 256 + 2 * cc];
        float z0 = -3.4e38f, z1 = -3.4e38f;
        int last = e - 1;
        for (int k = 0; k < e; k += 16) {
            uint4 ra = *(const uint4*)&row[k];
            uint4 rb = *(const uint4*)&row[k + 8];
            unsigned int rw[8] = {ra.x, ra.y, ra.z, ra.w, rb.x, rb.y, rb.z, rb.w};
            int j0 = rw[0] & 0xffff;
            unsigned int u[16];
#pragma unroll
            for (int tt = 0; tt < 16; tt++) {
                int raw = (rw[tt >> 1] >> ((tt & 1) * 16)) & 0xffff;
                int j = (k + tt <= last) ? raw : j0;
                u[tt] = Q2u[j * 128 + cc];
            }
#pragma unroll
            for (int tt = 0; tt < 16; tt++) {
                z0 = fmaxf(z0, bflo(u[tt]));
                z1 = fmaxf(z1, bfhi(u[tt]));
            }
        }
        float px = __uint_as_float((unsigned int)pv);
        float py = __uint_as_float((unsigned int)(pv >> 32));
        m0 = fmaxf(m0, sigm(px + z0));
        m1 = fmaxf(m1, sigm(py + z1));
    }
    if (curg >= 0 && m0 > 0.f) {
        int gb = curg * 256 + 2 * cc;
        atomicMax((unsigned int*)&g[gb + 0], __float_as_uint(m0));
        atomicMax((unsigned int*)&g[gb + 1], __float_as_uint(m1));
    }
}

__global__ void final_k(const float* __restrict__ g, const float* __restrict__ W3,
                        const float* __restrict__ b3, const float* __restrict__ W4,
                        const float* __restrict__ b4, float* __restrict__ out) {
    __shared__ float gs[256];
    __shared__ float ss[128];
    int b = blockIdx.x, t = threadIdx.x;
    gs[t] = g[b * 256 + t];
    gs[t + 128] = g[b * 256 + 128 + t];
    __syncthreads();
    float acc = b3[t];
#pragma unroll 8
    for (int k = 0; k < 256; k++) acc += gs[k] * W3[k * 128 + t];
    ss[t] = sigm(acc);
    __syncthreads();
    if (t < 10) {
        float o = b4[t];
#pragma unroll 8
        for (int k = 0; k < 128; k++) o += ss[k] * W4[k * 10 + t];
        out[b * 10 + t] = o;
    }
}

extern "C" void kernel_launch(void* const* d_in, const int* in_sizes, int n_in,
                              void* d_out, int out_size, void* d_ws, size_t ws_size,
                              hipStream_t stream) {
    const float* x  = (const float*)d_in[0];
    const void*  ei_raw = d_in[1];
    const void*  b_raw  = d_in[2];
    const float* W1 = (const float*)d_in[3];
    const float* b1 = (const float*)d_in[4];
    const float* W2 = (const float*)d_in[5];
    const float* b2 = (const float*)d_in[6];
    const float* W3 = (const float*)d_in[7];
    const float* b3 = (const float*)d_in[8];
    const float* W4 = (const float*)d_in[9];
    const float* b4 = (const float*)d_in[10];

    char* ws = (char*)d_ws;
    size_t off = 0;
    auto alloc = [&](size_t bytes) {
        void* p = ws + off;
        off += (bytes + 255) & ~(size_t)255;
        return p;
    };
    int*            bat     = (int*)alloc(N_NODES * 4);
    int*            cnt     = (int*)alloc(N_NODES * 4);
    unsigned short* csr_pad = (unsigned short*)alloc((size_t)N_NODES * STRIDE * 2);
    unsigned short* Q1      = (unsigned short*)alloc((size_t)N_NODES * 128 * 2);
    unsigned short* h1h     = (unsigned short*)alloc((size_t)N_NODES * 128 * 2);
    unsigned short* h1l     = (unsigned short*)alloc((size_t)N_NODES * 128 * 2);
    unsigned short* Bh      = (unsigned short*)alloc(512 * 128 * 2);
    unsigned short* Bl      = (unsigned short*)alloc(512 * 128 * 2);
    float*          P2      = (float*)alloc((size_t)N_NODES * 256 * 4);
    unsigned short* Q2      = (unsigned short*)alloc((size_t)N_NODES * 256 * 2);
    float*          g       = (float*)alloc(N_GRAPHS * 256 * 4);

    // ---- cooperative mega-kernel path ----
    const unsigned int* eiu = (const unsigned int*)ei_raw;
    const unsigned int* bru = (const unsigned int*)b_raw;
    float* outp = (float*)d_out;
    void* args[] = {(void*)&eiu, (void*)&bru, (void*)&x, (void*)&W1, (void*)&b1,
                    (void*)&W2, (void*)&b2, (void*)&W3, (void*)&b3, (void*)&W4, (void*)&b4,
                    (void*)&bat, (void*)&cnt, (void*)&csr_pad, (void*)&Q1,
                    (void*)&h1h, (void*)&h1l, (void*)&Bh, (void*)&Bl,
                    (void*)&P2, (void*)&Q2, (void*)&g, (void*)&outp};
    int occ = 0;
    hipError_t qerr = hipOccupancyMaxActiveBlocksPerMultiprocessor(&occ, mega_k, 256, 0);
    if (qerr != hipSuccess || occ < 1) occ = 4;  // 32KB LDS -> 4/CU always safe
    if (occ > 5) occ = 5;
    hipError_t err = hipLaunchCooperativeKernel((void*)mega_k, dim3((unsigned)occ * 256u),
                                                dim3(256), args, 0, stream);
    if (err == hipSuccess) return;

    // ---- fallback: r9 five-kernel path ----
    hipMemsetAsync(cnt, 0, N_NODES * 4, stream);
    prep_k<<<RB + RQ + RW + 1, 256, 0, stream>>>(
        eiu, bru, x, W1, W2, bat, cnt, csr_pad, Q1, Bh, Bl, g);
    econv1_k<<<N_NODES / 4, 256, 0, stream>>>(x, W1, b1, (const unsigned int*)Q1,
                                              cnt, csr_pad, h1h, h1l);
    gemm2_k<<<dim3((N_NODES + 63) / 64, 8), 256, 0, stream>>>(h1h, h1l, Bh, Bl, b2, P2, Q2, N_NODES);
    econv2_k<<<N_NODES / 16, 256, 0, stream>>>(P2, (const unsigned int*)Q2,
                                               cnt, csr_pad, bat, g);
    final_k<<<N_GRAPHS, 128, 0, stream>>>(g, W3, b3, W4, b4, (float*)d_out);
}

// Round 15
// 174.182 us; speedup vs baseline: 4.0568x; 4.0568x over previous
//
#include <hip/hip_runtime.h>

#define N_NODES  10000
#define N_EDGES  320000
#define N_GRAPHS 64
#define STRIDE   192   // padded adjacency row length (mean deg 32, P(deg>192) ~ 0)

// prep kernel role partition
#define RB 625    // repack+scatter blocks (2 edges/thread: ceil(320000/512))
#define RQ 157    // q1 blocks (ceil(10000/64))
#define RW 256    // w2-split blocks (512*128/256)

typedef __attribute__((ext_vector_type(8))) __bf16 bf16x8;
typedef __attribute__((ext_vector_type(4))) float f32x4;
typedef __attribute__((ext_vector_type(4))) unsigned int u32x4;

__device__ __forceinline__ float sigm(float z) { return 1.0f / (1.0f + __expf(-z)); }

// round-to-nearest-even f32 -> bf16 bits
__device__ __forceinline__ unsigned short f2bf(float f) {
    unsigned int u = __float_as_uint(f);
    return (unsigned short)((u + 0x7fffu + ((u >> 16) & 1u)) >> 16);
}
__device__ __forceinline__ float bf2f(unsigned short h) { return __uint_as_float(((unsigned int)h) << 16); }
__device__ __forceinline__ float bflo(unsigned int u) { return __uint_as_float(u << 16); }
__device__ __forceinline__ float bfhi(unsigned int u) { return __uint_as_float(u & 0xffff0000u); }

// ---------------- fused prep: repack+padded-CSR scatter | q1 | w2split | g-zero ----
__global__ __launch_bounds__(256) void prep_k(
        const unsigned int* __restrict__ ei_raw, const unsigned int* __restrict__ b_raw,
        const float* __restrict__ x, const float* __restrict__ W1,
        const float* __restrict__ W2,
        int* __restrict__ bat, int* __restrict__ cnt, unsigned short* __restrict__ csr_pad,
        unsigned short* __restrict__ Q1,
        unsigned short* __restrict__ Bh, unsigned short* __restrict__ Bl,
        float* __restrict__ g) {
    int bx = blockIdx.x, t = threadIdx.x;
    if (bx < RB) {
        // ---- per-block int-width self-detection (sample odd words of a 512-word window)
        __shared__ int snz[2];
        if (t < 2) snz[t] = 0;
        __syncthreads();
        {
            unsigned int wv = ei_raw[bx * 1024 + 2 * t + 1];   // max 624*1024+511 < 640000
            unsigned long long m = __ballot(wv != 0);
            if ((t & 63) == 0 && m) atomicAdd(&snz[0], __popcll(m));
        }
        if (bx * 256 < N_NODES) {
            int w0 = min(bx * 512, N_NODES - 512);
            unsigned int bv = b_raw[w0 + 2 * t + 1];
            unsigned long long m = __ballot(bv != 0);
            if ((t & 63) == 0 && m) atomicAdd(&snz[1], __popcll(m));
        }
        __syncthreads();
        int i32e = snz[0] > 16;
        const int* ei = (const int*)ei_raw;
        // ---- 2 edges per thread, vectorized
        int e0 = bx * 512 + 2 * t;   // e0, e0+1 < 320000 always (625*512 = 320000)
        int s0, s1, d0, d1;
        if (i32e) {
            uint2 sv = *(const uint2*)&ei[e0];
            uint2 dv = *(const uint2*)&ei[N_EDGES + e0];
            s0 = sv.x; s1 = sv.y; d0 = dv.x; d1 = dv.y;
        } else {
            uint4 sv = *(const uint4*)&ei[2 * e0];
            uint4 dv = *(const uint4*)&ei[2 * (N_EDGES + e0)];
            s0 = sv.x; s1 = sv.z; d0 = dv.x; d1 = dv.z;
        }
        int slot = atomicAdd(&cnt[d0], 1);
        if (slot < STRIDE) csr_pad[d0 * STRIDE + slot] = (unsigned short)s0;
        slot = atomicAdd(&cnt[d1], 1);
        if (slot < STRIDE) csr_pad[d1 * STRIDE + slot] = (unsigned short)s1;
        // ---- batch repack (first 40 blocks)
        int i = bx * 256 + t;
        if (i < N_NODES) {
            int i32b = snz[1] > 16;
            const int* bb = (const int*)b_raw;
            bat[i] = i32b ? bb[i] : bb[2 * i];
        }
    } else if (bx < RB + RQ) {
        // ---- Q1[n][c] = x[n]·W1[3:6][c] (bf16); 64 nodes per block
        __shared__ float xs[192];
        int c = t & 127, half = t >> 7;
        float k0 = W1[384 + c];
        float k1 = W1[512 + c];
        float k2 = W1[640 + c];
        int n0 = (bx - RB) * 64;
        int nmax = min(64, N_NODES - n0);
        if (t < 192) xs[t] = (t < nmax * 3) ? x[n0 * 3 + t] : 0.f;
        __syncthreads();
        for (int tt = 0; tt < 32; tt++) {
            int ln = 2 * tt + half;
            if (ln < nmax) {
                float v = xs[ln * 3 + 0] * k0 + xs[ln * 3 + 1] * k1 + xs[ln * 3 + 2] * k2;
                Q1[(n0 + ln) * 128 + c] = f2bf(v);
            }
        }
    } else if (bx < RB + RQ + RW) {
        // ---- W2 -> transposed split-bf16 B: Bh/Bl[nn][k]
        int idx = (bx - RB - RQ) * 256 + t;
        int nn = idx >> 7, k = idx & 127;
        float wc;
        if (nn < 256) wc = W2[k * 256 + nn] - W2[(128 + k) * 256 + nn];
        else          wc = W2[(128 + k) * 256 + (nn - 256)];
        unsigned short h = f2bf(wc);
        Bh[idx] = h;
        Bl[idx] = f2bf(wc - bf2f(h));
    } else {
        // ---- zero g (64*256 floats) with one block
        float4 z = make_float4(0.f, 0.f, 0.f, 0.f);
#pragma unroll
        for (int it = 0; it < 16; it++) *(float4*)&g[(t + it * 256) * 4] = z;
    }
}

// ---------------- EdgeConv1: 4 waves/block = 4 nodes; 16-deep gather; bias prefetched ----
__global__ __launch_bounds__(256) void econv1_k(
        const float* __restrict__ x, const float* __restrict__ W1, const float* __restrict__ b1,
        const unsigned int* __restrict__ Q1u,
        const int* __restrict__ cnt, const unsigned short* __restrict__ csr_pad,
        unsigned short* __restrict__ h1h, unsigned short* __restrict__ h1l) {
    int lane = threadIdx.x & 63;
    int i = blockIdx.x * 4 + (threadIdx.x >> 6);   // grid = 2500, 10000%4==0 -> in range
    int e = min(cnt[i], STRIDE);
    // prefetch bias operands early: independent of the gather chain, latency hides under it
    int c0 = 2 * lane, c1 = c0 + 1;
    float x0 = x[i * 3 + 0], x1 = x[i * 3 + 1], x2 = x[i * 3 + 2];
    float bb0 = b1[c0], bb1 = b1[c1];
    float wa0 = W1[c0] - W1[384 + c0];
    float wb0 = W1[128 + c0] - W1[512 + c0];
    float wc0 = W1[256 + c0] - W1[640 + c0];
    float wa1 = W1[c1] - W1[384 + c1];
    float wb1 = W1[128 + c1] - W1[512 + c1];
    float wc1 = W1[256 + c1] - W1[640 + c1];
    float o0 = 0.f, o1 = 0.f;
    if (e > 0) {
        const unsigned short* row = csr_pad + (size_t)i * STRIDE;
        float z0 = -3.4e38f, z1 = -3.4e38f;
        int last = e - 1;
        for (int k = 0; k < e; k += 16) {
            uint4 ra = *(const uint4*)&row[k];
            uint4 rb = *(const uint4*)&row[k + 8];
            unsigned int rw[8] = {ra.x, ra.y, ra.z, ra.w, rb.x, rb.y, rb.z, rb.w};
            int j0 = rw[0] & 0xffff;
            unsigned int u[16];
#pragma unroll
            for (int tt = 0; tt < 16; tt++) {
                int raw = (rw[tt >> 1] >> ((tt & 1) * 16)) & 0xffff;
                int j = (k + tt <= last) ? raw : j0;  // dup-pad: max is idempotent
                u[tt] = Q1u[j * 64 + lane];
            }
#pragma unroll
            for (int tt = 0; tt < 16; tt++) {
                z0 = fmaxf(z0, bflo(u[tt]));
                z1 = fmaxf(z1, bfhi(u[tt]));
            }
        }
        float p0 = bb0 + x0 * wa0 + x1 * wb0 + x2 * wc0;
        float p1 = bb1 + x0 * wa1 + x1 * wb1 + x2 * wc1;
        o0 = sigm(p0 + z0);
        o1 = sigm(p1 + z1);
    }
    unsigned short hh0 = f2bf(o0), hh1 = f2bf(o1);
    unsigned short hl0 = f2bf(o0 - bf2f(hh0)), hl1 = f2bf(o1 - bf2f(hh1));
    *(ushort2*)&h1h[i * 128 + 2 * lane] = make_ushort2(hh0, hh1);
    *(ushort2*)&h1l[i * 128 + 2 * lane] = make_ushort2(hl0, hl1);
}

// ---------------- GEMM2 via split-bf16 MFMA: [10000,128] @ [128,512] ----------------
__global__ __launch_bounds__(256) void gemm2_k(
        const unsigned short* __restrict__ Ahg, const unsigned short* __restrict__ Alg,
        const unsigned short* __restrict__ Bhg, const unsigned short* __restrict__ Blg,
        const float* __restrict__ b2, float* __restrict__ P2,
        unsigned short* __restrict__ Q2, int n) {
    __shared__ __align__(16) char smem[65536];
    char* Ahb = smem;
    char* Alb = smem + 16384;
    char* Bhb = smem + 32768;
    char* Blb = smem + 49152;
    int t = threadIdx.x;
    int m0 = blockIdx.x * 64;
    int n0 = blockIdx.y * 64;
#pragma unroll
    for (int it = 0; it < 4; it++) {
        int c = t + it * 256;
        int row = c >> 4, kb = c & 15;
        int dsa = (row * 256 + kb * 16) ^ ((row & 7) << 4);
        u32x4 va = {0u, 0u, 0u, 0u}, vl = {0u, 0u, 0u, 0u};
        if (m0 + row < n) {
            va = *(const u32x4*)&Ahg[(m0 + row) * 128 + kb * 8];
            vl = *(const u32x4*)&Alg[(m0 + row) * 128 + kb * 8];
        }
        *(u32x4*)(Ahb + dsa) = va;
        *(u32x4*)(Alb + dsa) = vl;
        *(u32x4*)(Bhb + dsa) = *(const u32x4*)&Bhg[(n0 + row) * 128 + kb * 8];
        *(u32x4*)(Blb + dsa) = *(const u32x4*)&Blg[(n0 + row) * 128 + kb * 8];
    }
    __syncthreads();

    int w = t >> 6, lane = t & 63;
    int lr = lane & 15, lg = lane >> 4;
    int am = 16 * w + lr;
    int abase = am * 256 + lg * 16;
    int asw = (am & 7) << 4;
    bf16x8 ah[4], al[4];
#pragma unroll
    for (int kk = 0; kk < 4; kk++) {
        int off = (abase + kk * 64) ^ asw;
        ah[kk] = *(const bf16x8*)(Ahb + off);
        al[kk] = *(const bf16x8*)(Alb + off);
    }
    int bsw = (lr & 7) << 4;
#pragma unroll
    for (int nt = 0; nt < 4; nt++) {
        int nb = (nt * 16 + lr) * 256 + lg * 16;
        f32x4 acc = {0.f, 0.f, 0.f, 0.f};
#pragma unroll
        for (int kk = 0; kk < 4; kk++) {
            int off = (nb + kk * 64) ^ bsw;
            bf16x8 bh = *(const bf16x8*)(Bhb + off);
            bf16x8 bl = *(const bf16x8*)(Blb + off);
            acc = __builtin_amdgcn_mfma_f32_16x16x32_bf16(ah[kk], bh, acc, 0, 0, 0);
            acc = __builtin_amdgcn_mfma_f32_16x16x32_bf16(al[kk], bh, acc, 0, 0, 0);
            acc = __builtin_amdgcn_mfma_f32_16x16x32_bf16(ah[kk], bl, acc, 0, 0, 0);
        }
        int colg = n0 + nt * 16 + lr;
        int mbase = m0 + 16 * w + 4 * lg;
        if (colg < 256) {
            float bias = b2[colg];
#pragma unroll
            for (int r = 0; r < 4; r++) {
                int m = mbase + r;
                if (m < n) P2[(size_t)m * 256 + colg] = acc[r] + bias;  // regular store: keep cache-hot
            }
        } else {
            int qc = colg - 256;
#pragma unroll
            for (int r = 0; r < 4; r++) {
                int m = mbase + r;
                if (m < n) Q2[(size_t)m * 256 + qc] = f2bf(acc[r]);
            }
        }
    }
}

// ---------------- EdgeConv2 + graph max-pool with block-level pre-reduction ----------------
__global__ __launch_bounds__(256) void econv2_k(
        const float* __restrict__ P2, const unsigned int* __restrict__ Q2u,
        const int* __restrict__ cnt, const unsigned short* __restrict__ csr_pad,
        const int* __restrict__ bat, float* __restrict__ g) {
    int lane = threadIdx.x & 63;
    int w = threadIdx.x >> 6;
    int half = w & 1, slot = w >> 1;
    int cc = half * 64 + lane;          // uint channel 0..127
    int base = blockIdx.x * 16;         // 625 * 16 = 10000 exactly
    float m0 = 0.f, m1 = 0.f;           // pooled max for current graph (sigm outputs > 0)
    int curg = -1;
    for (int nn = slot; nn < 16; nn += 2) {
        int i = base + nn;
        int bi = bat[i];
        if (bi != curg) {               // batch sorted -> graph changes monotonically
            if (curg >= 0 && m0 > 0.f) {
                int gb = curg * 256 + 2 * cc;
                atomicMax((unsigned int*)&g[gb + 0], __float_as_uint(m0));
                atomicMax((unsigned int*)&g[gb + 1], __float_as_uint(m1));
            }
            curg = bi;
            m0 = 0.f;
            m1 = 0.f;
        }
        int e = min(cnt[i], STRIDE);
        if (e == 0) continue;           // empty row -> h2 = 0, contributes nothing
        const unsigned short* row = csr_pad + (size_t)i * STRIDE;
        // prefetch epilogue operand: independent of gather chain
        unsigned long long pv = *(const unsigned long long*)&P2[(size_t)i * 256 + 2 * cc];
        float z0 = -3.4e38f, z1 = -3.4e38f;
        int last = e - 1;
        for (int k = 0; k < e; k += 16) {
            uint4 ra = *(const uint4*)&row[k];
            uint4 rb = *(const uint4*)&row[k + 8];
            unsigned int rw[8] = {ra.x, ra.y, ra.z, ra.w, rb.x, rb.y, rb.z, rb.w};
            int j0 = rw[0] & 0xffff;
            unsigned int u[16];
#pragma unroll
            for (int tt = 0; tt < 16; tt++) {
                int raw = (rw[tt >> 1] >> ((tt & 1) * 16)) & 0xffff;
                int j = (k + tt <= last) ? raw : j0;   // dup-pad: max is idempotent
                u[tt] = Q2u[j * 128 + cc];
            }
#pragma unroll
            for (int tt = 0; tt < 16; tt++) {
                z0 = fmaxf(z0, bflo(u[tt]));
                z1 = fmaxf(z1, bfhi(u[tt]));
            }
        }
        float px = __uint_as_float((unsigned int)pv);
        float py = __uint_as_float((unsigned int)(pv >> 32));
        m0 = fmaxf(m0, sigm(px + z0));
        m1 = fmaxf(m1, sigm(py + z1));
    }
    if (curg >= 0 && m0 > 0.f) {
        int gb = curg * 256 + 2 * cc;
        atomicMax((unsigned int*)&g[gb + 0], __float_as_uint(m0));
        atomicMax((unsigned int*)&g[gb + 1], __float_as_uint(m1));
    }
}

// ---------------- head: out = sigmoid(g@W3+b3)@W4+b4 ----------------
__global__ void final_k(const float* __restrict__ g, const float* __restrict__ W3,
                        const float* __restrict__ b3, const float* __restrict__ W4,
                        const float* __restrict__ b4, float* __restrict__ out) {
    __shared__ float gs[256];
    __shared__ float ss[128];
    int b = blockIdx.x, t = threadIdx.x;  // 128 threads
    gs[t] = g[b * 256 + t];
    gs[t + 128] = g[b * 256 + 128 + t];
    __syncthreads();
    float acc = b3[t];
#pragma unroll 8
    for (int k = 0; k < 256; k++) acc += gs[k] * W3[k * 128 + t];
    ss[t] = sigm(acc);
    __syncthreads();
    if (t < 10) {
        float o = b4[t];
#pragma unroll 8
        for (int k = 0; k < 128; k++) o += ss[k] * W4[k * 10 + t];
        out[b * 10 + t] = o;
    }
}

extern "C" void kernel_launch(void* const* d_in, const int* in_sizes, int n_in,
                              void* d_out, int out_size, void* d_ws, size_t ws_size,
                              hipStream_t stream) {
    const float* x  = (const float*)d_in[0];
    const void*  ei_raw = d_in[1];
    const void*  b_raw  = d_in[2];
    const float* W1 = (const float*)d_in[3];
    const float* b1 = (const float*)d_in[4];
    const float* W2 = (const float*)d_in[5];
    const float* b2 = (const float*)d_in[6];
    const float* W3 = (const float*)d_in[7];
    const float* b3 = (const float*)d_in[8];
    const float* W4 = (const float*)d_in[9];
    const float* b4 = (const float*)d_in[10];

    char* ws = (char*)d_ws;
    size_t off = 0;
    auto alloc = [&](size_t bytes) {
        void* p = ws + off;
        off += (bytes + 255) & ~(size_t)255;
        return p;
    };
    int*            bat     = (int*)alloc(N_NODES * 4);
    int*            cnt     = (int*)alloc(N_NODES * 4);
    unsigned short* csr_pad = (unsigned short*)alloc((size_t)N_NODES * STRIDE * 2);
    unsigned short* Q1      = (unsigned short*)alloc((size_t)N_NODES * 128 * 2);
    unsigned short* h1h     = (unsigned short*)alloc((size_t)N_NODES * 128 * 2);
    unsigned short* h1l     = (unsigned short*)alloc((size_t)N_NODES * 128 * 2);
    unsigned short* Bh      = (unsigned short*)alloc(512 * 128 * 2);
    unsigned short* Bl      = (unsigned short*)alloc(512 * 128 * 2);
    float*          P2      = (float*)alloc((size_t)N_NODES * 256 * 4);
    unsigned short* Q2      = (unsigned short*)alloc((size_t)N_NODES * 256 * 2);
    float*          g       = (float*)alloc(N_GRAPHS * 256 * 4);

    hipMemsetAsync(cnt, 0, N_NODES * 4, stream);

    prep_k<<<RB + RQ + RW + 1, 256, 0, stream>>>(
        (const unsigned int*)ei_raw, (const unsigned int*)b_raw, x, W1, W2,
        bat, cnt, csr_pad, Q1, Bh, Bl, g);

    econv1_k<<<N_NODES / 4, 256, 0, stream>>>(x, W1, b1, (const unsigned int*)Q1,
                                              cnt, csr_pad, h1h, h1l);
    gemm2_k<<<dim3((N_NODES + 63) / 64, 8), 256, 0, stream>>>(h1h, h1l, Bh, Bl, b2, P2, Q2, N_NODES);

    econv2_k<<<N_NODES / 16, 256, 0, stream>>>(P2, (const unsigned int*)Q2,
                                               cnt, csr_pad, bat, g);
    final_k<<<N_GRAPHS, 128, 0, stream>>>(g, W3, b3, W4, b4, (float*)d_out);
}